// Round 2
// baseline (312.032 us; speedup 1.0000x reference)
//
#include <hip/hip_runtime.h>
#include <math.h>

// Problem dims (fixed by reference)
#define NB 8
#define NC 3
#define NH 1024
#define NW 1024
#define KRAD 5      // 11x11 box
#define EPS 1e-6f

// Tiling
#define TH 32
#define TW 64
#define HALO_H (TH + 2 * KRAD)   // 42
#define HSTRIDE 65               // pad: bank = (row + col) % 32 -> 2-way (free)
#define NTHREADS 256
#define NUNITS (HALO_H * 8)      // 336 (row, col-group) units per block

__global__ __launch_bounds__(NTHREADS, 4)
void lcs_kernel(const float* __restrict__ x, const float* __restrict__ y,
                float* __restrict__ out) {
    // Only horizontal 11-tap sums live in LDS: 3 * 42 * 65 * 4 = 32760 B
    __shared__ float Hs[3][HALO_H][HSTRIDE];

    const int tid = threadIdx.x;
    const int w0 = blockIdx.x * TW;
    const int h0 = blockIdx.y * TH;
    const int b  = blockIdx.z;
    const size_t chan = (size_t)NH * NW;
    const float* xb = x + (size_t)b * NC * chan;
    const float* yb = y + (size_t)b * NC * chan;

    // ---- Phase H: horizontal sums straight from global (no raw-product LDS) ----
    // Unit u = (halo row, col-group of 8 output cols). Each unit loads a
    // 24-col window (6 aligned float4) per channel/tensor; float4s are fully
    // in- or out-of-bounds (boundaries at 0/1024 are 4-aligned), OOB -> 0.
    for (int u = tid; u < NUNITS; u += NTHREADS) {
        const int row  = u >> 3;
        const int colg = u & 7;
        const int gh   = h0 + row - KRAD;
        const int gw0  = w0 + colg * 8 - 8;   // first loaded column

        float hxx[8], hyy[8], hxy[8];
        #pragma unroll
        for (int j = 0; j < 8; ++j) { hxx[j] = 0.f; hyy[j] = 0.f; hxy[j] = 0.f; }

        if ((unsigned)gh < (unsigned)NH) {
            #pragma unroll
            for (int c = 0; c < NC; ++c) {
                const float* xr = xb + c * chan + (size_t)gh * NW;
                const float* yr = yb + c * chan + (size_t)gh * NW;
                float xv[24], yv[24];
                #pragma unroll
                for (int q = 0; q < 6; ++q) {
                    const int cs = gw0 + 4 * q;
                    const bool ok = (cs >= 0) && (cs <= NW - 4);
                    float4 a  = ok ? *(const float4*)(xr + cs) : make_float4(0.f, 0.f, 0.f, 0.f);
                    float4 bv = ok ? *(const float4*)(yr + cs) : make_float4(0.f, 0.f, 0.f, 0.f);
                    xv[4*q] = a.x;  xv[4*q+1] = a.y;  xv[4*q+2] = a.z;  xv[4*q+3] = a.w;
                    yv[4*q] = bv.x; yv[4*q+1] = bv.y; yv[4*q+2] = bv.z; yv[4*q+3] = bv.w;
                }
                // Output col j (local window cols j+3 .. j+13), sliding update.
                float sxx = 0.f, syy = 0.f, sxy = 0.f;
                #pragma unroll
                for (int m = 3; m <= 13; ++m) {
                    sxx += xv[m] * xv[m];
                    syy += yv[m] * yv[m];
                    sxy += xv[m] * yv[m];
                }
                hxx[0] += sxx; hyy[0] += syy; hxy[0] += sxy;
                #pragma unroll
                for (int j = 1; j < 8; ++j) {
                    sxx += xv[j+13] * xv[j+13] - xv[j+2] * xv[j+2];
                    syy += yv[j+13] * yv[j+13] - yv[j+2] * yv[j+2];
                    sxy += xv[j+13] * yv[j+13] - xv[j+2] * yv[j+2];
                    hxx[j] += sxx; hyy[j] += syy; hxy[j] += sxy;
                }
            }
        }
        #pragma unroll
        for (int j = 0; j < 8; ++j) {
            Hs[0][row][colg*8 + j] = hxx[j];
            Hs[1][row][colg*8 + j] = hyy[j];
            Hs[2][row][colg*8 + j] = hxy[j];
        }
    }
    __syncthreads();   // the ONLY barrier

    // ---- Phase V: vertical 11-tap running sums + finalize ----
    const int c     = tid & (TW - 1);    // 0..63 == lane -> stride-1 LDS reads
    const int rbase = (tid >> 6) * 8;    // 8 output rows per thread

    float acc[3][8];
    #pragma unroll
    for (int p = 0; p < 3; ++p) {
        float h[18];
        #pragma unroll
        for (int d = 0; d < 18; ++d) h[d] = Hs[p][rbase + d][c];
        float s = 0.f;
        #pragma unroll
        for (int d = 0; d < 11; ++d) s += h[d];
        acc[p][0] = s;
        #pragma unroll
        for (int j = 1; j < 8; ++j) { s += h[j+10] - h[j-1]; acc[p][j] = s; }
    }

    #pragma unroll
    for (int j = 0; j < 8; ++j) {
        const float denom = sqrtf(acc[0][j]) * sqrtf(acc[1][j]) + EPS;
        const size_t oidx = ((size_t)b * NH + (h0 + rbase + j)) * NW + (w0 + c);
        out[oidx] = acc[2][j] / denom;
    }
}

extern "C" void kernel_launch(void* const* d_in, const int* in_sizes, int n_in,
                              void* d_out, int out_size, void* d_ws, size_t ws_size,
                              hipStream_t stream) {
    const float* x = (const float*)d_in[0];
    const float* y = (const float*)d_in[1];
    float* out = (float*)d_out;
    dim3 grid(NW / TW, NH / TH, NB);   // 16 x 32 x 8 = 4096 blocks
    lcs_kernel<<<grid, NTHREADS, 0, stream>>>(x, y, out);
}

// Round 3
// 244.231 us; speedup vs baseline: 1.2776x; 1.2776x over previous
//
#include <hip/hip_runtime.h>
#include <math.h>

#define NB 8
#define NC 3
#define NH 1024
#define NW 1024
#define EPS 1e-6f

#define BAND 128            // output cols per wave
#define CH 32               // output rows per wave
#define KSTEPS (CH + 10)    // 42 h-rows per chunk
#define PADW (BAND + 16)    // 8 left pad + 128 + 8 right pad
#define NWAVES 4
#define NTHREADS 256
// total waves = 8 batches * 8 bands * 32 chunks = 2048 -> 512 blocks

__global__ __launch_bounds__(NTHREADS)
void lcs_kernel(const float* __restrict__ x, const float* __restrict__ y,
                float* __restrict__ out) {
    // wave-private LDS slices; same-wave write->read, NO __syncthreads anywhere
    __shared__ __align__(16) float P[NWAVES][3][PADW];

    const int tid = threadIdx.x;
    const int w   = tid >> 6;
    const int l   = tid & 63;

    const int gwid  = blockIdx.x * NWAVES + w;   // 0..2047
    const int b     = gwid >> 8;                 // batch
    const int rem   = gwid & 255;
    const int band0 = (rem & 7) * BAND;          // adjacent bands share halo in L2
    const int r0    = (rem >> 3) * CH;

    const size_t chan = (size_t)NH * NW;
    const float* xb = x + (size_t)b * NC * chan;
    const float* yb = y + (size_t)b * NC * chan;

    // lane load columns: main float2 at gc0 (padded slot 2l), extra (lanes 0..7)
    const int gc0 = band0 - 8 + 2 * l;                 // always < NW
    const int gcE = band0 - 8 + 2 * (64 + l);          // = band0 + 120 + 2l
    const bool m0 = (gc0 >= 0);
    const bool mE = (l < 8) && (gcE < NW);

    float2 nx[3], ny[3], exv[3], eyv[3];

    auto ldrow = [&](int gr) {
        if ((unsigned)gr < (unsigned)NH) {
            const size_t ro = (size_t)gr * NW;
            #pragma unroll
            for (int c = 0; c < 3; ++c) {
                const float* xr = xb + c * chan + ro;
                const float* yr = yb + c * chan + ro;
                nx[c]  = m0 ? *(const float2*)(xr + gc0) : make_float2(0.f, 0.f);
                ny[c]  = m0 ? *(const float2*)(yr + gc0) : make_float2(0.f, 0.f);
                exv[c] = mE ? *(const float2*)(xr + gcE) : make_float2(0.f, 0.f);
                eyv[c] = mE ? *(const float2*)(yr + gcE) : make_float2(0.f, 0.f);
            }
        } else {
            #pragma unroll
            for (int c = 0; c < 3; ++c) {
                nx[c]  = make_float2(0.f, 0.f); ny[c]  = make_float2(0.f, 0.f);
                exv[c] = make_float2(0.f, 0.f); eyv[c] = make_float2(0.f, 0.f);
            }
        }
    };

    ldrow(r0 - 5);   // prime pipeline with h-row k=0

    // vertical running sums + mod-11 ring (statically indexed after unroll)
    float2 ring[3][11];
    #pragma unroll
    for (int p = 0; p < 3; ++p)
        #pragma unroll
        for (int s = 0; s < 11; ++s) ring[p][s] = make_float2(0.f, 0.f);
    float2 vs[3] = {make_float2(0.f,0.f), make_float2(0.f,0.f), make_float2(0.f,0.f)};

    for (int g = 0; g < 4; ++g) {
        #pragma unroll
        for (int s = 0; s < 11; ++s) {
            const int k = g * 11 + s;
            if (k >= KSTEPS) continue;   // uniform; only g=3,s>=9

            // ---- products of current row -> wave LDS slice ----
            float2 pxx = make_float2(0.f,0.f), pyy = pxx, pxy = pxx;
            float2 qxx = pxx, qyy = pxx, qxy = pxx;
            #pragma unroll
            for (int c = 0; c < 3; ++c) {
                pxx.x += nx[c].x * nx[c].x;  pxx.y += nx[c].y * nx[c].y;
                pyy.x += ny[c].x * ny[c].x;  pyy.y += ny[c].y * ny[c].y;
                pxy.x += nx[c].x * ny[c].x;  pxy.y += nx[c].y * ny[c].y;
                qxx.x += exv[c].x * exv[c].x; qxx.y += exv[c].y * exv[c].y;
                qyy.x += eyv[c].x * eyv[c].x; qyy.y += eyv[c].y * eyv[c].y;
                qxy.x += exv[c].x * eyv[c].x; qxy.y += exv[c].y * eyv[c].y;
            }
            ((float2*)&P[w][0][0])[l] = pxx;
            ((float2*)&P[w][1][0])[l] = pyy;
            ((float2*)&P[w][2][0])[l] = pxy;
            if (l < 8) {
                ((float2*)&P[w][0][0])[64 + l] = qxx;
                ((float2*)&P[w][1][0])[64 + l] = qyy;
                ((float2*)&P[w][2][0])[64 + l] = qxy;
            }

            // ---- prefetch next row (stays in flight; no barrier drain) ----
            if (k + 1 < KSTEPS) ldrow(r0 - 4 + k);

            __builtin_amdgcn_wave_barrier();   // pin writes above reads

            // ---- horizontal 11-tap per plane, vertical running sum ----
            #pragma unroll
            for (int p = 0; p < 3; ++p) {
                const float* Pp = &P[w][p][0];
                float2 t[7];
                #pragma unroll
                for (int j = 0; j < 7; ++j)
                    t[j] = *(const float2*)(Pp + 2 * l + 2 + 2 * j);
                // out col 2l: padded cols 2l+3..2l+13 ; out col 2l+1: +1 window
                float h0 = ((t[0].y + t[1].x) + (t[1].y + t[2].x))
                         + ((t[2].y + t[3].x) + (t[3].y + t[4].x))
                         + ((t[4].y + t[5].x) + t[5].y);
                float h1 = h0 - t[0].y + t[6].x;
                vs[p].x += h0 - ring[p][s].x;
                vs[p].y += h1 - ring[p][s].y;
                ring[p][s].x = h0;
                ring[p][s].y = h1;
            }

            __builtin_amdgcn_wave_barrier();   // pin reads above next step's writes

            // ---- emit output row (k>=10) ----
            if (k >= 10) {
                const int orow = r0 + k - 10;
                float2 o;
                o.x = vs[2].x / (sqrtf(vs[0].x) * sqrtf(vs[1].x) + EPS);
                o.y = vs[2].y / (sqrtf(vs[0].y) * sqrtf(vs[1].y) + EPS);
                *(float2*)(out + ((size_t)b * NH + orow) * NW + band0 + 2 * l) = o;
            }
        }
    }
}

extern "C" void kernel_launch(void* const* d_in, const int* in_sizes, int n_in,
                              void* d_out, int out_size, void* d_ws, size_t ws_size,
                              hipStream_t stream) {
    const float* x = (const float*)d_in[0];
    const float* y = (const float*)d_in[1];
    float* out = (float*)d_out;
    lcs_kernel<<<dim3(512), dim3(NTHREADS), 0, stream>>>(x, y, out);
}

// Round 4
// 241.279 us; speedup vs baseline: 1.2932x; 1.0122x over previous
//
#include <hip/hip_runtime.h>
#include <math.h>

#define NB 8
#define NC 3
#define NH 1024
#define NW 1024
#define EPS 1e-6f

#define BAND 128            // output cols per wave (float2 per lane)
#define CH 32               // output rows per wave
#define KSTEPS (CH + 10)    // 42 product rows per chunk
#define PADW 144            // 8 pad | 128 | 8 pad  (floats)
// grid: 8 batches * 8 bands * 32 chunks = 2048 blocks of 64 threads (1 wave)

__global__ __launch_bounds__(64, 2)
void lcs_kernel(const float* __restrict__ x, const float* __restrict__ y,
                float* __restrict__ out) {
    __shared__ __align__(16) float P[3][PADW];   // 1728 B, wave-private

    const int l   = threadIdx.x;                 // 0..63
    const int bid = blockIdx.x;
    const int b     = bid >> 8;                  // scalar (blockIdx-derived)
    const int rem   = bid & 255;
    const int band0 = (rem & 7) * BAND;
    const int r0    = (rem >> 3) * CH;

    const size_t chan = (size_t)NH * NW;
    const float* xb = x + (size_t)b * NC * chan;
    const float* yb = y + (size_t)b * NC * chan;

    // lane column offsets (constant across steps) + edge masks folded to floats
    const int gc0 = band0 - 8 + 2 * l;                 // main float2 col
    const int gcE = band0 + 120 + 2 * l;               // extra float2 col (lanes 0..7)
    const float mm = (gc0 >= 0) ? 1.f : 0.f;           // left edge, band0==0 lanes 0..3
    const float me = (l < 8 && gcE + 1 <= NW - 1) ? 1.f : 0.f;
    const int o0 = (gc0 >= 0) ? gc0 : 0;               // clamped -> always valid
    const int oE = (me > 0.f) ? gcE : 0;

    float2 cur[12], nxt[12];
    // d[0..2]=x main ch, d[3..5]=y main, d[6..8]=x extra, d[9..11]=y extra
    auto ldrow = [&](int gr, float2* d) {
        const int rc = gr < 0 ? 0 : (gr > NH - 1 ? NH - 1 : gr);   // scalar clamp
        const size_t ro = (size_t)rc * NW;
        #pragma unroll
        for (int c = 0; c < 3; ++c) {
            const float* xr = xb + c * chan + ro;   // scalar base -> saddr form
            const float* yr = yb + c * chan + ro;
            d[c]     = *(const float2*)(xr + o0);
            d[3 + c] = *(const float2*)(yr + o0);
            d[6 + c] = *(const float2*)(xr + oE);
            d[9 + c] = *(const float2*)(yr + oE);
        }
    };

    ldrow(r0 - 5, cur);   // prime k=0

    float2 ring[3][11];
    #pragma unroll
    for (int p = 0; p < 3; ++p)
        #pragma unroll
        for (int s = 0; s < 11; ++s) ring[p][s] = make_float2(0.f, 0.f);
    float2 vs[3] = {make_float2(0.f,0.f), make_float2(0.f,0.f), make_float2(0.f,0.f)};

    for (int g = 0; g < 4; ++g) {                 // rolled (code stays ~11 steps)
        #pragma unroll
        for (int s = 0; s < 11; ++s) {            // unrolled -> static ring index
            const int k = g * 11 + s;
            if (k >= KSTEPS) continue;            // uniform, only g==3,s>=9

            // ---- prefetch next row first: max time in flight ----
            if (k + 1 < KSTEPS) ldrow(r0 - 4 + k, nxt);

            // ---- channel-reduced products of current row ----
            float2 pxx = make_float2(0.f,0.f), pyy = pxx, pxy = pxx;
            float2 qxx = pxx, qyy = pxx, qxy = pxx;
            #pragma unroll
            for (int c = 0; c < 3; ++c) {
                const float2 xm = cur[c],   ym = cur[3+c];
                const float2 xe = cur[6+c], ye = cur[9+c];
                pxx.x += xm.x*xm.x; pxx.y += xm.y*xm.y;
                pyy.x += ym.x*ym.x; pyy.y += ym.y*ym.y;
                pxy.x += xm.x*ym.x; pxy.y += xm.y*ym.y;
                qxx.x += xe.x*xe.x; qxx.y += xe.y*xe.y;
                qyy.x += ye.x*ye.x; qyy.y += ye.y*ye.y;
                qxy.x += xe.x*ye.x; qxy.y += xe.y*ye.y;
            }
            // fold row+lane OOB masks (values at clamped addrs are finite)
            const int gr = r0 - 5 + k;
            const float rmf = (gr >= 0 && gr < NH) ? 1.f : 0.f;   // scalar
            const float cmM = rmf * mm, cmE = rmf * me;
            pxx.x *= cmM; pxx.y *= cmM; pyy.x *= cmM; pyy.y *= cmM;
            pxy.x *= cmM; pxy.y *= cmM;
            qxx.x *= cmE; qxx.y *= cmE; qyy.x *= cmE; qyy.y *= cmE;
            qxy.x *= cmE; qxy.y *= cmE;

            ((float2*)&P[0][0])[l] = pxx;
            ((float2*)&P[1][0])[l] = pyy;
            ((float2*)&P[2][0])[l] = pxy;
            if (l < 8) {
                ((float2*)&P[0][0])[64 + l] = qxx;
                ((float2*)&P[1][0])[64 + l] = qyy;
                ((float2*)&P[2][0])[64 + l] = qxy;
            }
            __builtin_amdgcn_wave_barrier();   // pin LDS writes above reads

            // ---- horizontal 11-tap + vertical running sum (ring) ----
            #pragma unroll
            for (int p = 0; p < 3; ++p) {
                const float* Pp = &P[p][0];
                float2 t[7];
                #pragma unroll
                for (int j = 0; j < 7; ++j)
                    t[j] = *(const float2*)(Pp + 2*l + 2 + 2*j);
                float h0 = ((t[0].y + t[1].x) + (t[1].y + t[2].x))
                         + ((t[2].y + t[3].x) + (t[3].y + t[4].x))
                         + ((t[4].y + t[5].x) + t[5].y);
                float h1 = h0 - t[0].y + t[6].x;
                vs[p].x += h0 - ring[p][s].x;
                vs[p].y += h1 - ring[p][s].y;
                ring[p][s].x = h0;
                ring[p][s].y = h1;
            }
            __builtin_amdgcn_wave_barrier();   // pin reads above next step's writes

            // ---- emit ----
            if (k >= 10) {
                const int orow = r0 + k - 10;
                const float d0 = __builtin_amdgcn_sqrtf(vs[0].x) *
                                 __builtin_amdgcn_sqrtf(vs[1].x) + EPS;
                const float d1 = __builtin_amdgcn_sqrtf(vs[0].y) *
                                 __builtin_amdgcn_sqrtf(vs[1].y) + EPS;
                float2 o;
                o.x = vs[2].x * __builtin_amdgcn_rcpf(d0);
                o.y = vs[2].y * __builtin_amdgcn_rcpf(d1);
                *(float2*)(out + ((size_t)b * NH + orow) * NW + band0 + 2*l) = o;
            }

            // rotate prefetch regs (renamed across unrolled copies)
            if (k + 1 < KSTEPS) {
                #pragma unroll
                for (int i = 0; i < 12; ++i) cur[i] = nxt[i];
            }
        }
    }
}

extern "C" void kernel_launch(void* const* d_in, const int* in_sizes, int n_in,
                              void* d_out, int out_size, void* d_ws, size_t ws_size,
                              hipStream_t stream) {
    const float* x = (const float*)d_in[0];
    const float* y = (const float*)d_in[1];
    float* out = (float*)d_out;
    lcs_kernel<<<dim3(2048), dim3(64), 0, stream>>>(x, y, out);
}